// Round 2
// baseline (1694.710 us; speedup 1.0000x reference)
//
#include <hip/hip_runtime.h>
#include <math.h>

typedef __attribute__((ext_vector_type(8))) short bf16x8;
typedef __attribute__((ext_vector_type(4))) float f32x4;

static __device__ __forceinline__ short f2bf(float f) {
  unsigned u = __builtin_bit_cast(unsigned, f);
  u += 0x7fffu + ((u >> 16) & 1u);
  return (short)(u >> 16);
}
static __device__ __forceinline__ float bf2f(short s) {
  unsigned u = ((unsigned)(unsigned short)s) << 16;
  return __builtin_bit_cast(float, u);
}
static __device__ __forceinline__ f32x4 mfma16(bf16x8 a, bf16x8 b, f32x4 c) {
  return __builtin_amdgcn_mfma_f32_16x16x32_bf16(a, b, c, 0, 0, 0);
}
static __device__ __forceinline__ bf16x8 pack8v(f32x4 a, f32x4 b) {
  bf16x8 r;
  r[0]=f2bf(a[0]); r[1]=f2bf(a[1]); r[2]=f2bf(a[2]); r[3]=f2bf(a[3]);
  r[4]=f2bf(b[0]); r[5]=f2bf(b[1]); r[6]=f2bf(b[2]); r[7]=f2bf(b[3]);
  return r;
}

// ---------------- cast item_emb -> bf16 (row-major) ----------------
__global__ __launch_bounds__(256) void cast_ebf(const float* __restrict__ E, short* __restrict__ Ebf) {
  int i = blockIdx.x * 256 + threadIdx.x;
  if (i < 50001 * 128) Ebf[i] = f2bf(E[i]);
}

// ---------------- build E^T bf16 [128][50048] (zero-padded) ----------------
__global__ __launch_bounds__(256) void build_et(const float* __restrict__ E, short* __restrict__ Et) {
  __shared__ float tile[64][132];
  const int v0 = blockIdx.x * 64;
  const int tid = threadIdx.x;
  const int r = tid >> 2, ks = (tid & 3) * 32;
  const int v = v0 + r;
  for (int j = 0; j < 32; j += 4) {
    f32x4 x = {0.f, 0.f, 0.f, 0.f};
    if (v < 50001) x = *(const f32x4*)(E + (size_t)v * 128 + ks + j);
    *(f32x4*)&tile[r][ks + j] = x;
  }
  __syncthreads();
  const int k = tid >> 1, vs = (tid & 1) * 32;
  for (int j = 0; j < 32; ++j)
    Et[(size_t)k * 50048 + v0 + vs + j] = f2bf(tile[vs + j][k]);
}

// ---------------- GRU recurrence: 1 barrier/step, x prefetched from Ebf into regs ----------------
__global__ __launch_bounds__(512) void gru_rec_kernel(
    const int* __restrict__ seq0, const int* __restrict__ seq1,
    const int* __restrict__ seq2, const int* __restrict__ seq3,
    const short* __restrict__ Ebf,
    const float* __restrict__ Wih, const float* __restrict__ Whh,
    const float* __restrict__ bih, const float* __restrict__ bhh,
    float* __restrict__ e_out)
{
  const int beh = blockIdx.x >> 5;
  const int r0 = (blockIdx.x & 31) * 16;
  const int* seq; int T;
  if (beh == 0)      { seq = seq0; T = 50; }
  else if (beh == 1) { seq = seq1; T = 50; }
  else if (beh == 2) { seq = seq2; T = 50; }
  else               { seq = seq3; T = 200; }

  const int tid = threadIdx.x;
  const int wave = tid >> 6;
  const int lane = tid & 63;
  const int lrow = lane & 15;
  const int lk8 = lane >> 4;
  const int bcol = wave * 16 + lrow;

  __shared__ short h0[16][140];
  __shared__ short h1[16][140];
  __shared__ int seq_lds[16 * 200];

  // Wih/Whh B-fragments in registers (96 VGPR)
  bf16x8 wif[3][4], whf[3][4];
  const float* WihB = Wih + (size_t)beh * 384 * 128;
  const float* WhhB = Whh + (size_t)beh * 384 * 128;
#pragma unroll
  for (int g = 0; g < 3; ++g) {
    const int wr = g * 128 + bcol;
#pragma unroll
    for (int kt = 0; kt < 4; ++kt) {
      const int k0 = kt * 32 + lk8 * 8;
      f32x4 a0 = *(const f32x4*)(WihB + (size_t)wr * 128 + k0);
      f32x4 a1 = *(const f32x4*)(WihB + (size_t)wr * 128 + k0 + 4);
      f32x4 b0 = *(const f32x4*)(WhhB + (size_t)wr * 128 + k0);
      f32x4 b1 = *(const f32x4*)(WhhB + (size_t)wr * 128 + k0 + 4);
      wif[g][kt] = pack8v(a0, a1);
      whf[g][kt] = pack8v(b0, b1);
    }
  }
  const float bir = bih[beh * 384 + bcol];
  const float biz = bih[beh * 384 + 128 + bcol];
  const float bin_ = bih[beh * 384 + 256 + bcol];
  const float bhr = bhh[beh * 384 + bcol];
  const float bhz = bhh[beh * 384 + 128 + bcol];
  const float bhn = bhh[beh * 384 + 256 + bcol];

  // stage seq rows into LDS; zero h0
  {
    const int rr = tid >> 5, cc = tid & 31;
    for (int j = cc; j < T; j += 32)
      seq_lds[rr * T + j] = seq[(size_t)(r0 + rr) * T + j];
  }
  for (int i = tid; i < 16 * 140; i += 512) ((short*)h0)[i] = 0;
  float hreg[4] = {0.f, 0.f, 0.f, 0.f};
  __syncthreads();

#define ISSUE_X(t_, dst_) do {                                   \
    const int v_ = seq_lds[lrow * T + (t_)];                     \
    const short* rp_ = Ebf + (size_t)v_ * 128 + lk8 * 8;         \
    dst_[0] = *(const bf16x8*)(rp_);                             \
    dst_[1] = *(const bf16x8*)(rp_ + 32);                        \
    dst_[2] = *(const bf16x8*)(rp_ + 64);                        \
    dst_[3] = *(const bf16x8*)(rp_ + 96);                        \
  } while (0)

  bf16x8 xp[4];
  ISSUE_X(0, xp);

  short (*hin)[140] = h0;
  short (*hout)[140] = h1;

  for (int t = 0; t < T; ++t) {
    bf16x8 ax[4];
    ax[0] = xp[0]; ax[1] = xp[1]; ax[2] = xp[2]; ax[3] = xp[3];
    if (t + 1 < T) ISSUE_X(t + 1, xp);   // prefetch next step's x

    bf16x8 ah[4];
#pragma unroll
    for (int kt = 0; kt < 4; ++kt)
      ah[kt] = *(const bf16x8*)&hin[lrow][kt * 32 + lk8 * 8];

    f32x4 gr = {0,0,0,0}, gz = {0,0,0,0}, gn = {0,0,0,0};
    f32x4 hr = {0,0,0,0}, hz = {0,0,0,0}, hn = {0,0,0,0};
#pragma unroll
    for (int kt = 0; kt < 4; ++kt) {
      gr = mfma16(ax[kt], wif[0][kt], gr);
      gz = mfma16(ax[kt], wif[1][kt], gz);
      gn = mfma16(ax[kt], wif[2][kt], gn);
      hr = mfma16(ah[kt], whf[0][kt], hr);
      hz = mfma16(ah[kt], whf[1][kt], hz);
      hn = mfma16(ah[kt], whf[2][kt], hn);
    }
#pragma unroll
    for (int e2 = 0; e2 < 4; ++e2) {
      const float rr = 1.f / (1.f + __expf(-(gr[e2] + bir + hr[e2] + bhr)));
      const float zz = 1.f / (1.f + __expf(-(gz[e2] + biz + hz[e2] + bhz)));
      const float nn = tanhf(gn[e2] + bin_ + rr * (hn[e2] + bhn));
      hreg[e2] = (1.f - zz) * nn + zz * hreg[e2];
      hout[lk8 * 4 + e2][bcol] = f2bf(hreg[e2]);
    }
    __syncthreads();
    short (*tmp)[140] = hin; hin = hout; hout = tmp;
  }
#undef ISSUE_X

#pragma unroll
  for (int e2 = 0; e2 < 4; ++e2)
    e_out[(size_t)(r0 + lk8 * 4 + e2) * 512 + bcol * 4 + beh] = hreg[e2];
}

// ---------------- caps: c = softmax(b), v = alpha * sum_h c*u (u recomputed), v_ = ||v||*ws+bias ----------------
__global__ __launch_bounds__(256) void caps_v_kernel(
    const float* __restrict__ b_state, const float* __restrict__ e_buf,
    const float* __restrict__ W, const float* __restrict__ w_scale,
    const float* __restrict__ bias_vec, const float* __restrict__ alpha,
    float* __restrict__ v_buf, float* __restrict__ vn_buf)
{
  __shared__ float e_lds[4][128][4];
  __shared__ float stat_m[4][128];
  __shared__ float stat_i[4][128];
  const int g0 = blockIdx.x * 4;
  const int tid = threadIdx.x;
  for (int i = tid; i < 2048; i += 256) ((float*)e_lds)[i] = e_buf[(size_t)g0 * 512 + i];
  const int wv = tid >> 6, ln = tid & 63;
  for (int ri = wv; ri < 512; ri += 4) {
    const int g = ri >> 7, h = ri & 127;
    const float* row = b_state + (size_t)(g0 + g) * 16384 + h * 128;
    const float x0 = row[ln], x1 = row[ln + 64];
    float m = fmaxf(x0, x1);
#pragma unroll
    for (int off = 32; off > 0; off >>= 1) m = fmaxf(m, __shfl_xor(m, off));
    float s = __expf(x0 - m) + __expf(x1 - m);
#pragma unroll
    for (int off = 32; off > 0; off >>= 1) s += __shfl_xor(s, off);
    if (ln == 0) { stat_m[g][h] = m; stat_i[g][h] = 1.f / s; }
  }
  __syncthreads();
  const int c = tid >> 1, dh = (tid & 1) * 4;
  f32x4 acc[4] = {{0,0,0,0},{0,0,0,0},{0,0,0,0},{0,0,0,0}};
  for (int h = 0; h < 128; ++h) {
    float cv[4];
#pragma unroll
    for (int g = 0; g < 4; ++g)
      cv[g] = __expf(b_state[(size_t)(g0 + g) * 16384 + h * 128 + c] - stat_m[g][h]) * stat_i[g][h];
#pragma unroll
    for (int t4 = 0; t4 < 4; ++t4) {
      const f32x4 w4 = *(const f32x4*)(W + ((size_t)(h * 4 + t4) * 128 + c) * 8 + dh);
#pragma unroll
      for (int g = 0; g < 4; ++g) acc[g] += (cv[g] * e_lds[g][h][t4]) * w4;
    }
  }
  const float al = alpha[0];
#pragma unroll
  for (int g = 0; g < 4; ++g) {
    acc[g] *= al;
    *(f32x4*)(v_buf + (size_t)(g0 + g) * 1024 + c * 8 + dh) = acc[g];
    float ss = acc[g][0]*acc[g][0] + acc[g][1]*acc[g][1] + acc[g][2]*acc[g][2] + acc[g][3]*acc[g][3];
    ss += __shfl_xor(ss, 1);
    if ((tid & 1) == 0) vn_buf[(g0 + g) * 128 + c] = sqrtf(ss) * w_scale[c] + bias_vec[c];
  }
}

// ---------------- logits = vn @ E^T (MFMA bf16), into d_out ----------------
__global__ __launch_bounds__(512) void logits_kernel(
    const float* __restrict__ vn, const short* __restrict__ Ebf,
    float* __restrict__ out)
{
  __shared__ short et[64][136];
  const int n0 = blockIdx.x * 64;
  const int m0 = blockIdx.y * 128;
  const int tid = threadIdx.x;
  const int wave = tid >> 6, lane = tid & 63, lrow = lane & 15, lk8 = lane >> 4;
  {
    const int r = tid >> 3, ks = (tid & 7) * 16;
    const int v = n0 + r;
    bf16x8 a = {0,0,0,0,0,0,0,0}, b = {0,0,0,0,0,0,0,0};
    if (v < 50001) {
      a = *(const bf16x8*)(Ebf + (size_t)v * 128 + ks);
      b = *(const bf16x8*)(Ebf + (size_t)v * 128 + ks + 8);
    }
    *(bf16x8*)&et[r][ks] = a;
    *(bf16x8*)&et[r][ks + 8] = b;
  }
  __syncthreads();
  const int arow = m0 + wave * 16 + lrow;
  bf16x8 afr[4];
#pragma unroll
  for (int kt = 0; kt < 4; ++kt) {
    const float* p = vn + (size_t)arow * 128 + kt * 32 + lk8 * 8;
    afr[kt] = pack8v(*(const f32x4*)p, *(const f32x4*)(p + 4));
  }
  f32x4 acc[4] = {{0,0,0,0},{0,0,0,0},{0,0,0,0},{0,0,0,0}};
#pragma unroll
  for (int kt = 0; kt < 4; ++kt) {
#pragma unroll
    for (int nt = 0; nt < 4; ++nt) {
      const bf16x8 bfr = *(const bf16x8*)&et[nt * 16 + lrow][kt * 32 + lk8 * 8];
      acc[nt] = mfma16(afr[kt], bfr, acc[nt]);
    }
  }
#pragma unroll
  for (int nt = 0; nt < 4; ++nt) {
    const int col = n0 + nt * 16 + lrow;
    if (col < 50001) {
      const int row = m0 + wave * 16 + lk8 * 4;
#pragma unroll
      for (int e2 = 0; e2 < 4; ++e2)
        out[(size_t)(row + e2) * 50001 + col] = acc[nt][e2];
    }
  }
}

// ---------------- per-row softmax stats over 50001 logits ----------------
__global__ __launch_bounds__(256) void rowstats_kernel(
    const float* __restrict__ out, float* __restrict__ row_m, float* __restrict__ row_inv)
{
  const int b = blockIdx.x;
  const int tid = threadIdx.x;
  const float* row = out + (size_t)b * 50001;
  float m = -1e30f, s = 0.f;
  for (int i = tid; i < 50001; i += 256) {
    const float x = row[i];
    const float nm = fmaxf(m, x);
    s = s * __expf(m - nm) + __expf(x - nm);
    m = nm;
  }
#pragma unroll
  for (int off = 32; off > 0; off >>= 1) {
    const float m2 = __shfl_xor(m, off), s2 = __shfl_xor(s, off);
    const float nm = fmaxf(m, m2);
    s = s * __expf(m - nm) + s2 * __expf(m2 - nm);
    m = nm;
  }
  __shared__ float ms[4], ss[4];
  const int wv = tid >> 6, ln = tid & 63;
  if (ln == 0) { ms[wv] = m; ss[wv] = s; }
  __syncthreads();
  if (tid == 0) {
    float M = ms[0], S = ss[0];
    for (int w = 1; w < 4; ++w) {
      const float nm = fmaxf(M, ms[w]);
      S = S * __expf(M - nm) + ss[w] * __expf(ms[w] - nm);
      M = nm;
    }
    row_m[b] = M;
    row_inv[b] = 1.f / S;
  }
}

// ---------------- p = softmax(logits) @ E  (split-K MFMA, atomic accumulate) ----------------
__global__ __launch_bounds__(256) void pgemm_kernel(
    const float* __restrict__ out, const short* __restrict__ Et,
    const float* __restrict__ row_m, const float* __restrict__ row_inv,
    float* __restrict__ p_buf)
{
  const int tid = threadIdx.x;
  const int wave = tid >> 6, lane = tid & 63, lrow = lane & 15, lk8 = lane >> 4;
  const int m0 = blockIdx.y * 64;
  const int row = m0 + wave * 16 + lrow;
  const float rm = row_m[row], ri = row_inv[row];
  const float* lp = out + (size_t)row * 50001;
  const int kbeg = blockIdx.x * 1024;
  f32x4 acc[8] = {{0,0,0,0},{0,0,0,0},{0,0,0,0},{0,0,0,0},
                  {0,0,0,0},{0,0,0,0},{0,0,0,0},{0,0,0,0}};
  if (kbeg + 1024 <= 50001) {
    // full chunk: no boundary guards in the hot loop
    for (int v0 = kbeg; v0 < kbeg + 1024; v0 += 32) {
      const int kb = v0 + lk8 * 8;
      float x[8];
      __builtin_memcpy(x, lp + kb, 32);
      bf16x8 afr;
#pragma unroll
      for (int j = 0; j < 8; ++j) afr[j] = f2bf(__expf(x[j] - rm) * ri);
#pragma unroll
      for (int nt = 0; nt < 8; ++nt) {
        const bf16x8 bfr = *(const bf16x8*)(Et + (size_t)(nt * 16 + lrow) * 50048 + kb);
        acc[nt] = mfma16(afr, bfr, acc[nt]);
      }
    }
  } else {
    const int kend = 50001;
    for (int v0 = kbeg; v0 < kend; v0 += 32) {
      const int kb = v0 + lk8 * 8;
      float x[8];
#pragma unroll
      for (int j = 0; j < 8; ++j) x[j] = (kb + j < 50001) ? lp[kb + j] : rm - 100.f;
      bf16x8 afr;
#pragma unroll
      for (int j = 0; j < 8; ++j) afr[j] = f2bf(__expf(x[j] - rm) * ri);
#pragma unroll
      for (int nt = 0; nt < 8; ++nt) {
        const bf16x8 bfr = *(const bf16x8*)(Et + (size_t)(nt * 16 + lrow) * 50048 + kb);
        acc[nt] = mfma16(afr, bfr, acc[nt]);
      }
    }
  }
#pragma unroll
  for (int nt = 0; nt < 8; ++nt)
#pragma unroll
    for (int e2 = 0; e2 < 4; ++e2)
      atomicAdd(&p_buf[(size_t)(m0 + wave * 16 + lk8 * 4 + e2) * 128 + nt * 16 + lrow], acc[nt][e2]);
}

// ---------------- coef = concat(p, v) @ W_coef ----------------
__global__ __launch_bounds__(256) void coef_kernel(
    const float* __restrict__ p_buf, const float* __restrict__ v_buf,
    const float* __restrict__ W_coef, float* __restrict__ coef_buf)
{
  __shared__ float p_lds[4][128];
  const int g0 = blockIdx.x * 4;
  const int tid = threadIdx.x;
  for (int i = tid; i < 512; i += 256) ((float*)p_lds)[i] = p_buf[(size_t)g0 * 128 + i];
  __syncthreads();
  const int c = tid >> 1, dh = (tid & 1) * 4;
  float vg[4][8];
#pragma unroll
  for (int g = 0; g < 4; ++g) {
    const f32x4 va = *(const f32x4*)(v_buf + (size_t)(g0 + g) * 1024 + c * 8);
    const f32x4 vb = *(const f32x4*)(v_buf + (size_t)(g0 + g) * 1024 + c * 8 + 4);
    vg[g][0]=va[0]; vg[g][1]=va[1]; vg[g][2]=va[2]; vg[g][3]=va[3];
    vg[g][4]=vb[0]; vg[g][5]=vb[1]; vg[g][6]=vb[2]; vg[g][7]=vb[3];
  }
  const float* wc = W_coef + (size_t)c * 1088 + dh;
  f32x4 acc[4] = {{0,0,0,0},{0,0,0,0},{0,0,0,0},{0,0,0,0}};
  for (int dp = 0; dp < 128; ++dp) {
    const f32x4 w4 = *(const f32x4*)(wc + (size_t)dp * 8);
#pragma unroll
    for (int g = 0; g < 4; ++g) acc[g] += p_lds[g][dp] * w4;
  }
#pragma unroll
  for (int q = 0; q < 8; ++q) {
    const f32x4 w4 = *(const f32x4*)(wc + (size_t)(128 + q) * 8);
#pragma unroll
    for (int g = 0; g < 4; ++g) acc[g] += vg[g][q] * w4;
  }
#pragma unroll
  for (int g = 0; g < 4; ++g)
    *(f32x4*)(coef_buf + (size_t)(g0 + g) * 1024 + c * 8 + dh) = acc[g];
}

// ---------------- b += sum_t e * (sum_d W * coef) ----------------
__global__ __launch_bounds__(256) void bupd_kernel(
    const float* __restrict__ coef_buf, const float* __restrict__ e_buf,
    const float* __restrict__ W, float* __restrict__ b_state)
{
  __shared__ float e_lds[4][128][4];
  const int g0 = blockIdx.x * 4;
  const int tid = threadIdx.x;
  for (int i = tid; i < 2048; i += 256) ((float*)e_lds)[i] = e_buf[(size_t)g0 * 512 + i];
  __syncthreads();
  const int c = tid >> 1, dh = (tid & 1) * 4;
  f32x4 cf[4];
#pragma unroll
  for (int g = 0; g < 4; ++g)
    cf[g] = *(const f32x4*)(coef_buf + (size_t)(g0 + g) * 1024 + c * 8 + dh);
  for (int h = 0; h < 128; ++h) {
    float accg[4] = {0.f, 0.f, 0.f, 0.f};
#pragma unroll
    for (int t4 = 0; t4 < 4; ++t4) {
      const f32x4 w4 = *(const f32x4*)(W + ((size_t)(h * 4 + t4) * 128 + c) * 8 + dh);
#pragma unroll
      for (int g = 0; g < 4; ++g) {
        const float d4 = w4[0]*cf[g][0] + w4[1]*cf[g][1] + w4[2]*cf[g][2] + w4[3]*cf[g][3];
        accg[g] += e_lds[g][h][t4] * d4;
      }
    }
#pragma unroll
    for (int g = 0; g < 4; ++g) {
      const float full = accg[g] + __shfl_xor(accg[g], 1);
      if ((tid & 1) == 0)
        b_state[(size_t)(g0 + g) * 16384 + h * 128 + c] += full;
    }
  }
}

extern "C" void kernel_launch(void* const* d_in, const int* in_sizes, int n_in,
                              void* d_out, int out_size, void* d_ws, size_t ws_size,
                              hipStream_t stream) {
  const int* seq0 = (const int*)d_in[0];
  const int* seq1 = (const int*)d_in[1];
  const int* seq2 = (const int*)d_in[2];
  const int* seq3 = (const int*)d_in[3];
  const float* item_emb = (const float*)d_in[4];
  const float* Wih = (const float*)d_in[5];
  const float* Whh = (const float*)d_in[6];
  const float* bih = (const float*)d_in[7];
  const float* bhh = (const float*)d_in[8];
  const float* W = (const float*)d_in[9];
  const float* w_scale = (const float*)d_in[10];
  const float* bias_vec = (const float*)d_in[11];
  const float* alpha = (const float*)d_in[12];
  const float* W_coef = (const float*)d_in[13];
  float* out = (float*)d_out;

  char* ws = (char*)d_ws;
  float* e_buf    = (float*)(ws);                 // 1,048,576 B
  float* b_state  = (float*)(ws + 1048576);       // 33,554,432 B
  float* v_buf    = (float*)(ws + 34603008);      // 2,097,152 B
  float* vn_buf   = (float*)(ws + 36700160);      // 262,144 B
  float* p_buf    = (float*)(ws + 36962304);      // 262,144 B
  float* coef_buf = (float*)(ws + 37224448);      // 2,097,152 B
  float* row_m    = (float*)(ws + 39321600);      // 2,048 B
  float* row_inv  = (float*)(ws + 39323648);      // 2,048 B
  short* Ebf      = (short*)(ws + 39325696);      // 12,800,256 B
  short* Et       = (short*)(ws + 52125952);      // 12,812,288 B  (total ~64.9 MB)

  hipMemsetAsync(b_state, 0, 33554432, stream);
  cast_ebf<<<dim3(25001), 256, 0, stream>>>(item_emb, Ebf);
  build_et<<<dim3(782), 256, 0, stream>>>(item_emb, Et);
  gru_rec_kernel<<<dim3(128), 512, 0, stream>>>(seq0, seq1, seq2, seq3, Ebf,
                                                Wih, Whh, bih, bhh, e_buf);
  for (int it = 0; it < 2; ++it) {
    caps_v_kernel<<<dim3(128), 256, 0, stream>>>(b_state, e_buf, W, w_scale, bias_vec,
                                                 alpha, v_buf, vn_buf);
    logits_kernel<<<dim3(782, 4), 512, 0, stream>>>(vn_buf, Ebf, out);
    rowstats_kernel<<<dim3(512), 256, 0, stream>>>(out, row_m, row_inv);
    hipMemsetAsync(p_buf, 0, 262144, stream);
    pgemm_kernel<<<dim3(49, 8), 256, 0, stream>>>(out, Et, row_m, row_inv, p_buf);
    coef_kernel<<<dim3(128), 256, 0, stream>>>(p_buf, v_buf, W_coef, coef_buf);
    bupd_kernel<<<dim3(128), 256, 0, stream>>>(coef_buf, e_buf, W, b_state);
  }
  caps_v_kernel<<<dim3(128), 256, 0, stream>>>(b_state, e_buf, W, w_scale, bias_vec,
                                               alpha, v_buf, vn_buf);
  logits_kernel<<<dim3(782, 4), 512, 0, stream>>>(vn_buf, Ebf, out);
}

// Round 3
// 1342.780 us; speedup vs baseline: 1.2621x; 1.2621x over previous
//
#include <hip/hip_runtime.h>
#include <math.h>

typedef __attribute__((ext_vector_type(8))) short bf16x8;
typedef __attribute__((ext_vector_type(4))) float f32x4;

static __device__ __forceinline__ short f2bf(float f) {
  unsigned u = __builtin_bit_cast(unsigned, f);
  u += 0x7fffu + ((u >> 16) & 1u);
  return (short)(u >> 16);
}
static __device__ __forceinline__ f32x4 mfma16(bf16x8 a, bf16x8 b, f32x4 c) {
  return __builtin_amdgcn_mfma_f32_16x16x32_bf16(a, b, c, 0, 0, 0);
}
static __device__ __forceinline__ bf16x8 pack8v(f32x4 a, f32x4 b) {
  bf16x8 r;
  r[0]=f2bf(a[0]); r[1]=f2bf(a[1]); r[2]=f2bf(a[2]); r[3]=f2bf(a[3]);
  r[4]=f2bf(b[0]); r[5]=f2bf(b[1]); r[6]=f2bf(b[2]); r[7]=f2bf(b[3]);
  return r;
}

// ---------------- cast item_emb -> bf16 (row-major) ----------------
__global__ __launch_bounds__(256) void cast_ebf(const float* __restrict__ E, short* __restrict__ Ebf) {
  int i = blockIdx.x * 256 + threadIdx.x;
  if (i < 50001 * 128) Ebf[i] = f2bf(E[i]);
}

// ---------------- build E^T bf16 [128][50048] (zero-padded) ----------------
__global__ __launch_bounds__(256) void build_et(const float* __restrict__ E, short* __restrict__ Et) {
  __shared__ float tile[64][132];
  const int v0 = blockIdx.x * 64;
  const int tid = threadIdx.x;
  const int r = tid >> 2, ks = (tid & 3) * 32;
  const int v = v0 + r;
  for (int j = 0; j < 32; j += 4) {
    f32x4 x = {0.f, 0.f, 0.f, 0.f};
    if (v < 50001) x = *(const f32x4*)(E + (size_t)v * 128 + ks + j);
    *(f32x4*)&tile[r][ks + j] = x;
  }
  __syncthreads();
  const int k = tid >> 1, vs = (tid & 1) * 32;
  for (int j = 0; j < 32; ++j)
    Et[(size_t)k * 50048 + v0 + vs + j] = f2bf(tile[vs + j][k]);
}

// ---------------- GRU recurrence: no spills (launch_bounds 512,2), 1 barrier/step ----------------
__global__ __launch_bounds__(512, 2) void gru_rec_kernel(
    const int* __restrict__ seq0, const int* __restrict__ seq1,
    const int* __restrict__ seq2, const int* __restrict__ seq3,
    const short* __restrict__ Ebf,
    const float* __restrict__ Wih, const float* __restrict__ Whh,
    const float* __restrict__ bih, const float* __restrict__ bhh,
    float* __restrict__ e_out)
{
  const int beh = blockIdx.x >> 5;
  const int r0 = (blockIdx.x & 31) * 16;
  const int* seq; int T;
  if (beh == 0)      { seq = seq0; T = 50; }
  else if (beh == 1) { seq = seq1; T = 50; }
  else if (beh == 2) { seq = seq2; T = 50; }
  else               { seq = seq3; T = 200; }

  const int tid = threadIdx.x;
  const int wave = tid >> 6;
  const int lane = tid & 63;
  const int lrow = lane & 15;
  const int lk8 = lane >> 4;
  const int bcol = wave * 16 + lrow;

  __shared__ short h0[16][140];
  __shared__ short h1[16][140];
  __shared__ int seq_lds[16 * 200];

  // Wih/Whh B-fragments in registers (192 VGPR) -- (512,2) caps at 256, no spill
  bf16x8 wif[3][4], whf[3][4];
  const float* WihB = Wih + (size_t)beh * 384 * 128;
  const float* WhhB = Whh + (size_t)beh * 384 * 128;
#pragma unroll
  for (int g = 0; g < 3; ++g) {
    const int wr = g * 128 + bcol;
#pragma unroll
    for (int kt = 0; kt < 4; ++kt) {
      const int k0 = kt * 32 + lk8 * 8;
      f32x4 a0 = *(const f32x4*)(WihB + (size_t)wr * 128 + k0);
      f32x4 a1 = *(const f32x4*)(WihB + (size_t)wr * 128 + k0 + 4);
      f32x4 b0 = *(const f32x4*)(WhhB + (size_t)wr * 128 + k0);
      f32x4 b1 = *(const f32x4*)(WhhB + (size_t)wr * 128 + k0 + 4);
      wif[g][kt] = pack8v(a0, a1);
      whf[g][kt] = pack8v(b0, b1);
    }
  }
  const float bir = bih[beh * 384 + bcol];
  const float biz = bih[beh * 384 + 128 + bcol];
  const float bin_ = bih[beh * 384 + 256 + bcol];
  const float bhr = bhh[beh * 384 + bcol];
  const float bhz = bhh[beh * 384 + 128 + bcol];
  const float bhn = bhh[beh * 384 + 256 + bcol];

  // stage seq rows into LDS; zero h0
  {
    const int rr = tid >> 5, cc = tid & 31;
    for (int j = cc; j < T; j += 32)
      seq_lds[rr * T + j] = seq[(size_t)(r0 + rr) * T + j];
  }
  for (int i = tid; i < 16 * 140; i += 512) ((short*)h0)[i] = 0;
  float hreg[4] = {0.f, 0.f, 0.f, 0.f};
  __syncthreads();

#define ISSUE_X(t_, dst_) do {                                   \
    const int v_ = seq_lds[lrow * T + (t_)];                     \
    const short* rp_ = Ebf + (size_t)v_ * 128 + lk8 * 8;         \
    dst_[0] = *(const bf16x8*)(rp_);                             \
    dst_[1] = *(const bf16x8*)(rp_ + 32);                        \
    dst_[2] = *(const bf16x8*)(rp_ + 64);                        \
    dst_[3] = *(const bf16x8*)(rp_ + 96);                        \
  } while (0)

  bf16x8 xp[4];
  ISSUE_X(0, xp);

  short (*hin)[140] = h0;
  short (*hout)[140] = h1;

  for (int t = 0; t < T; ++t) {
    bf16x8 ax[4];
    ax[0] = xp[0]; ax[1] = xp[1]; ax[2] = xp[2]; ax[3] = xp[3];
    if (t + 1 < T) ISSUE_X(t + 1, xp);   // prefetch next step's x

    bf16x8 ah[4];
#pragma unroll
    for (int kt = 0; kt < 4; ++kt)
      ah[kt] = *(const bf16x8*)&hin[lrow][kt * 32 + lk8 * 8];

    f32x4 gr = {0,0,0,0}, gz = {0,0,0,0}, gn = {0,0,0,0};
    f32x4 hr = {0,0,0,0}, hz = {0,0,0,0}, hn = {0,0,0,0};
#pragma unroll
    for (int kt = 0; kt < 4; ++kt) {
      gr = mfma16(ax[kt], wif[0][kt], gr);
      gz = mfma16(ax[kt], wif[1][kt], gz);
      gn = mfma16(ax[kt], wif[2][kt], gn);
      hr = mfma16(ah[kt], whf[0][kt], hr);
      hz = mfma16(ah[kt], whf[1][kt], hz);
      hn = mfma16(ah[kt], whf[2][kt], hn);
    }
#pragma unroll
    for (int e2 = 0; e2 < 4; ++e2) {
      const float rr = __fdividef(1.f, 1.f + __expf(-(gr[e2] + bir + hr[e2] + bhr)));
      const float zz = __fdividef(1.f, 1.f + __expf(-(gz[e2] + biz + hz[e2] + bhz)));
      const float ty = __expf(-2.f * (gn[e2] + bin_ + rr * (hn[e2] + bhn)));
      const float nn = __fdividef(1.f - ty, 1.f + ty);   // tanh
      hreg[e2] = (1.f - zz) * nn + zz * hreg[e2];
      hout[lk8 * 4 + e2][bcol] = f2bf(hreg[e2]);
    }
    __syncthreads();
    short (*tmp)[140] = hin; hin = hout; hout = tmp;
  }
#undef ISSUE_X

#pragma unroll
  for (int e2 = 0; e2 < 4; ++e2)
    e_out[(size_t)(r0 + lk8 * 4 + e2) * 512 + bcol * 4 + beh] = hreg[e2];
}

// ---------------- caps: c = softmax(b), v = alpha * sum_h c*u, v_ = ||v||*ws+bias (512 thr, h-split) ----------------
__global__ __launch_bounds__(512) void caps_v_kernel(
    const float* __restrict__ b_state, const float* __restrict__ e_buf,
    const float* __restrict__ W, const float* __restrict__ w_scale,
    const float* __restrict__ bias_vec, const float* __restrict__ alpha,
    float* __restrict__ v_buf, float* __restrict__ vn_buf)
{
  __shared__ float e_lds[4][128][4];
  __shared__ float stat_m[4][128];
  __shared__ float stat_i[4][128];
  __shared__ float red[256][4][4];
  const int g0 = blockIdx.x * 4;
  const int tid = threadIdx.x;
  for (int i = tid; i < 2048; i += 512) ((float*)e_lds)[i] = e_buf[(size_t)g0 * 512 + i];
  const int wv = tid >> 6, ln = tid & 63;
  for (int ri = wv; ri < 512; ri += 8) {
    const int g = ri >> 7, h = ri & 127;
    const float* row = b_state + (size_t)(g0 + g) * 16384 + h * 128;
    const float x0 = row[ln], x1 = row[ln + 64];
    float m = fmaxf(x0, x1);
#pragma unroll
    for (int off = 32; off > 0; off >>= 1) m = fmaxf(m, __shfl_xor(m, off));
    float s = __expf(x0 - m) + __expf(x1 - m);
#pragma unroll
    for (int off = 32; off > 0; off >>= 1) s += __shfl_xor(s, off);
    if (ln == 0) { stat_m[g][h] = m; stat_i[g][h] = 1.f / s; }
  }
  __syncthreads();
  const int half = tid >> 8;
  const int t8 = tid & 255;
  const int c = t8 >> 1, dh = (t8 & 1) * 4;
  f32x4 acc[4] = {{0,0,0,0},{0,0,0,0},{0,0,0,0},{0,0,0,0}};
  const int hbeg = half * 64, hend = hbeg + 64;
  for (int h = hbeg; h < hend; ++h) {
    float cv[4];
#pragma unroll
    for (int g = 0; g < 4; ++g)
      cv[g] = __expf(b_state[(size_t)(g0 + g) * 16384 + h * 128 + c] - stat_m[g][h]) * stat_i[g][h];
#pragma unroll
    for (int t4 = 0; t4 < 4; ++t4) {
      const f32x4 w4 = *(const f32x4*)(W + ((size_t)(h * 4 + t4) * 128 + c) * 8 + dh);
#pragma unroll
      for (int g = 0; g < 4; ++g) acc[g] += (cv[g] * e_lds[g][h][t4]) * w4;
    }
  }
  if (half == 1) {
#pragma unroll
    for (int g = 0; g < 4; ++g) *(f32x4*)&red[t8][g][0] = acc[g];
  }
  __syncthreads();
  if (half == 0) {
    const float al = alpha[0];
#pragma unroll
    for (int g = 0; g < 4; ++g) {
      acc[g] = (acc[g] + *(const f32x4*)&red[t8][g][0]) * al;
      *(f32x4*)(v_buf + (size_t)(g0 + g) * 1024 + c * 8 + dh) = acc[g];
      float ss = acc[g][0]*acc[g][0] + acc[g][1]*acc[g][1] + acc[g][2]*acc[g][2] + acc[g][3]*acc[g][3];
      ss += __shfl_xor(ss, 1);
      if ((tid & 1) == 0) vn_buf[(g0 + g) * 128 + c] = sqrtf(ss) * w_scale[c] + bias_vec[c];
    }
  }
}

// ---------------- logits = vn @ E^T (MFMA bf16), into d_out ----------------
__global__ __launch_bounds__(512) void logits_kernel(
    const float* __restrict__ vn, const short* __restrict__ Ebf,
    float* __restrict__ out)
{
  __shared__ short et[64][136];
  const int n0 = blockIdx.x * 64;
  const int m0 = blockIdx.y * 128;
  const int tid = threadIdx.x;
  const int wave = tid >> 6, lane = tid & 63, lrow = lane & 15, lk8 = lane >> 4;
  {
    const int r = tid >> 3, ks = (tid & 7) * 16;
    const int v = n0 + r;
    bf16x8 a = {0,0,0,0,0,0,0,0}, b = {0,0,0,0,0,0,0,0};
    if (v < 50001) {
      a = *(const bf16x8*)(Ebf + (size_t)v * 128 + ks);
      b = *(const bf16x8*)(Ebf + (size_t)v * 128 + ks + 8);
    }
    *(bf16x8*)&et[r][ks] = a;
    *(bf16x8*)&et[r][ks + 8] = b;
  }
  __syncthreads();
  const int arow = m0 + wave * 16 + lrow;
  bf16x8 afr[4];
#pragma unroll
  for (int kt = 0; kt < 4; ++kt) {
    const float* p = vn + (size_t)arow * 128 + kt * 32 + lk8 * 8;
    afr[kt] = pack8v(*(const f32x4*)p, *(const f32x4*)(p + 4));
  }
  f32x4 acc[4] = {{0,0,0,0},{0,0,0,0},{0,0,0,0},{0,0,0,0}};
#pragma unroll
  for (int kt = 0; kt < 4; ++kt) {
#pragma unroll
    for (int nt = 0; nt < 4; ++nt) {
      const bf16x8 bfr = *(const bf16x8*)&et[nt * 16 + lrow][kt * 32 + lk8 * 8];
      acc[nt] = mfma16(afr[kt], bfr, acc[nt]);
    }
  }
#pragma unroll
  for (int nt = 0; nt < 4; ++nt) {
    const int col = n0 + nt * 16 + lrow;
    if (col < 50001) {
      const int row = m0 + wave * 16 + lk8 * 4;
#pragma unroll
      for (int e2 = 0; e2 < 4; ++e2)
        out[(size_t)(row + e2) * 50001 + col] = acc[nt][e2];
    }
  }
}

// ---------------- per-row softmax stats over 50001 logits ----------------
__global__ __launch_bounds__(256) void rowstats_kernel(
    const float* __restrict__ out, float* __restrict__ row_m, float* __restrict__ row_inv)
{
  const int b = blockIdx.x;
  const int tid = threadIdx.x;
  const float* row = out + (size_t)b * 50001;
  float m = -1e30f, s = 0.f;
  for (int i = tid; i < 50001; i += 256) {
    const float x = row[i];
    const float nm = fmaxf(m, x);
    s = s * __expf(m - nm) + __expf(x - nm);
    m = nm;
  }
#pragma unroll
  for (int off = 32; off > 0; off >>= 1) {
    const float m2 = __shfl_xor(m, off), s2 = __shfl_xor(s, off);
    const float nm = fmaxf(m, m2);
    s = s * __expf(m - nm) + s2 * __expf(m2 - nm);
    m = nm;
  }
  __shared__ float ms[4], ss[4];
  const int wv = tid >> 6, ln = tid & 63;
  if (ln == 0) { ms[wv] = m; ss[wv] = s; }
  __syncthreads();
  if (tid == 0) {
    float M = ms[0], S = ss[0];
    for (int w = 1; w < 4; ++w) {
      const float nm = fmaxf(M, ms[w]);
      S = S * __expf(M - nm) + ss[w] * __expf(ms[w] - nm);
      M = nm;
    }
    row_m[b] = M;
    row_inv[b] = 1.f / S;
  }
}

// ---------------- p = softmax(logits) @ E  (split-K MFMA, atomic accumulate) ----------------
__global__ __launch_bounds__(256) void pgemm_kernel(
    const float* __restrict__ out, const short* __restrict__ Et,
    const float* __restrict__ row_m, const float* __restrict__ row_inv,
    float* __restrict__ p_buf)
{
  const int tid = threadIdx.x;
  const int wave = tid >> 6, lane = tid & 63, lrow = lane & 15, lk8 = lane >> 4;
  const int m0 = blockIdx.y * 64;
  const int row = m0 + wave * 16 + lrow;
  const float rm = row_m[row], ri = row_inv[row];
  const float* lp = out + (size_t)row * 50001;
  const int kbeg = blockIdx.x * 1024;
  f32x4 acc[8] = {{0,0,0,0},{0,0,0,0},{0,0,0,0},{0,0,0,0},
                  {0,0,0,0},{0,0,0,0},{0,0,0,0},{0,0,0,0}};
  if (kbeg + 1024 <= 50001) {
    for (int v0 = kbeg; v0 < kbeg + 1024; v0 += 32) {
      const int kb = v0 + lk8 * 8;
      float x[8];
      __builtin_memcpy(x, lp + kb, 32);
      bf16x8 afr;
#pragma unroll
      for (int j = 0; j < 8; ++j) afr[j] = f2bf(__expf(x[j] - rm) * ri);
#pragma unroll
      for (int nt = 0; nt < 8; ++nt) {
        const bf16x8 bfr = *(const bf16x8*)(Et + (size_t)(nt * 16 + lrow) * 50048 + kb);
        acc[nt] = mfma16(afr, bfr, acc[nt]);
      }
    }
  } else {
    const int kend = 50001;
    for (int v0 = kbeg; v0 < kend; v0 += 32) {
      const int kb = v0 + lk8 * 8;
      float x[8];
#pragma unroll
      for (int j = 0; j < 8; ++j) x[j] = (kb + j < 50001) ? lp[kb + j] : rm - 100.f;
      bf16x8 afr;
#pragma unroll
      for (int j = 0; j < 8; ++j) afr[j] = f2bf(__expf(x[j] - rm) * ri);
#pragma unroll
      for (int nt = 0; nt < 8; ++nt) {
        const bf16x8 bfr = *(const bf16x8*)(Et + (size_t)(nt * 16 + lrow) * 50048 + kb);
        acc[nt] = mfma16(afr, bfr, acc[nt]);
      }
    }
  }
#pragma unroll
  for (int nt = 0; nt < 8; ++nt)
#pragma unroll
    for (int e2 = 0; e2 < 4; ++e2)
      atomicAdd(&p_buf[(size_t)(m0 + wave * 16 + lk8 * 4 + e2) * 128 + nt * 16 + lrow], acc[nt][e2]);
}

// ---------------- coef = concat(p, v) @ W_coef ----------------
__global__ __launch_bounds__(256) void coef_kernel(
    const float* __restrict__ p_buf, const float* __restrict__ v_buf,
    const float* __restrict__ W_coef, float* __restrict__ coef_buf)
{
  __shared__ float p_lds[4][128];
  const int g0 = blockIdx.x * 4;
  const int tid = threadIdx.x;
  for (int i = tid; i < 512; i += 256) ((float*)p_lds)[i] = p_buf[(size_t)g0 * 128 + i];
  __syncthreads();
  const int c = tid >> 1, dh = (tid & 1) * 4;
  float vg[4][8];
#pragma unroll
  for (int g = 0; g < 4; ++g) {
    const f32x4 va = *(const f32x4*)(v_buf + (size_t)(g0 + g) * 1024 + c * 8);
    const f32x4 vb = *(const f32x4*)(v_buf + (size_t)(g0 + g) * 1024 + c * 8 + 4);
    vg[g][0]=va[0]; vg[g][1]=va[1]; vg[g][2]=va[2]; vg[g][3]=va[3];
    vg[g][4]=vb[0]; vg[g][5]=vb[1]; vg[g][6]=vb[2]; vg[g][7]=vb[3];
  }
  const float* wc = W_coef + (size_t)c * 1088 + dh;
  f32x4 acc[4] = {{0,0,0,0},{0,0,0,0},{0,0,0,0},{0,0,0,0}};
  for (int dp = 0; dp < 128; ++dp) {
    const f32x4 w4 = *(const f32x4*)(wc + (size_t)dp * 8);
#pragma unroll
    for (int g = 0; g < 4; ++g) acc[g] += p_lds[g][dp] * w4;
  }
#pragma unroll
  for (int q = 0; q < 8; ++q) {
    const f32x4 w4 = *(const f32x4*)(wc + (size_t)(128 + q) * 8);
#pragma unroll
    for (int g = 0; g < 4; ++g) acc[g] += vg[g][q] * w4;
  }
#pragma unroll
  for (int g = 0; g < 4; ++g)
    *(f32x4*)(coef_buf + (size_t)(g0 + g) * 1024 + c * 8 + dh) = acc[g];
}

// ---------------- b += sum_t e * (sum_d W * coef)  (512 thr, h-partitioned) ----------------
__global__ __launch_bounds__(512) void bupd_kernel(
    const float* __restrict__ coef_buf, const float* __restrict__ e_buf,
    const float* __restrict__ W, float* __restrict__ b_state)
{
  __shared__ float e_lds[4][128][4];
  const int g0 = blockIdx.x * 4;
  const int tid = threadIdx.x;
  for (int i = tid; i < 2048; i += 512) ((float*)e_lds)[i] = e_buf[(size_t)g0 * 512 + i];
  __syncthreads();
  const int half = tid >> 8;
  const int t8 = tid & 255;
  const int c = t8 >> 1, dh = (t8 & 1) * 4;
  f32x4 cf[4];
#pragma unroll
  for (int g = 0; g < 4; ++g)
    cf[g] = *(const f32x4*)(coef_buf + (size_t)(g0 + g) * 1024 + c * 8 + dh);
  const int hbeg = half * 64, hend = hbeg + 64;
  for (int h = hbeg; h < hend; ++h) {
    float accg[4] = {0.f, 0.f, 0.f, 0.f};
#pragma unroll
    for (int t4 = 0; t4 < 4; ++t4) {
      const f32x4 w4 = *(const f32x4*)(W + ((size_t)(h * 4 + t4) * 128 + c) * 8 + dh);
#pragma unroll
      for (int g = 0; g < 4; ++g) {
        const float d4 = w4[0]*cf[g][0] + w4[1]*cf[g][1] + w4[2]*cf[g][2] + w4[3]*cf[g][3];
        accg[g] += e_lds[g][h][t4] * d4;
      }
    }
#pragma unroll
    for (int g = 0; g < 4; ++g) {
      const float full = accg[g] + __shfl_xor(accg[g], 1);
      if ((tid & 1) == 0)
        b_state[(size_t)(g0 + g) * 16384 + h * 128 + c] += full;
    }
  }
}

extern "C" void kernel_launch(void* const* d_in, const int* in_sizes, int n_in,
                              void* d_out, int out_size, void* d_ws, size_t ws_size,
                              hipStream_t stream) {
  const int* seq0 = (const int*)d_in[0];
  const int* seq1 = (const int*)d_in[1];
  const int* seq2 = (const int*)d_in[2];
  const int* seq3 = (const int*)d_in[3];
  const float* item_emb = (const float*)d_in[4];
  const float* Wih = (const float*)d_in[5];
  const float* Whh = (const float*)d_in[6];
  const float* bih = (const float*)d_in[7];
  const float* bhh = (const float*)d_in[8];
  const float* W = (const float*)d_in[9];
  const float* w_scale = (const float*)d_in[10];
  const float* bias_vec = (const float*)d_in[11];
  const float* alpha = (const float*)d_in[12];
  const float* W_coef = (const float*)d_in[13];
  float* out = (float*)d_out;

  char* ws = (char*)d_ws;
  float* e_buf    = (float*)(ws);                 // 1,048,576 B
  float* b_state  = (float*)(ws + 1048576);       // 33,554,432 B
  float* v_buf    = (float*)(ws + 34603008);      // 2,097,152 B
  float* vn_buf   = (float*)(ws + 36700160);      // 262,144 B
  float* p_buf    = (float*)(ws + 36962304);      // 262,144 B
  float* coef_buf = (float*)(ws + 37224448);      // 2,097,152 B
  float* row_m    = (float*)(ws + 39321600);      // 2,048 B
  float* row_inv  = (float*)(ws + 39323648);      // 2,048 B
  short* Ebf      = (short*)(ws + 39325696);      // 12,800,256 B
  short* Et       = (short*)(ws + 52125952);      // 12,812,288 B  (total ~64.9 MB)

  hipMemsetAsync(b_state, 0, 33554432, stream);
  cast_ebf<<<dim3(25001), 256, 0, stream>>>(item_emb, Ebf);
  build_et<<<dim3(782), 256, 0, stream>>>(item_emb, Et);
  gru_rec_kernel<<<dim3(128), 512, 0, stream>>>(seq0, seq1, seq2, seq3, Ebf,
                                                Wih, Whh, bih, bhh, e_buf);
  for (int it = 0; it < 2; ++it) {
    caps_v_kernel<<<dim3(128), 512, 0, stream>>>(b_state, e_buf, W, w_scale, bias_vec,
                                                 alpha, v_buf, vn_buf);
    logits_kernel<<<dim3(782, 4), 512, 0, stream>>>(vn_buf, Ebf, out);
    rowstats_kernel<<<dim3(512), 256, 0, stream>>>(out, row_m, row_inv);
    hipMemsetAsync(p_buf, 0, 262144, stream);
    pgemm_kernel<<<dim3(49, 8), 256, 0, stream>>>(out, Et, row_m, row_inv, p_buf);
    coef_kernel<<<dim3(128), 256, 0, stream>>>(p_buf, v_buf, W_coef, coef_buf);
    bupd_kernel<<<dim3(128), 512, 0, stream>>>(coef_buf, e_buf, W, b_state);
  }
  caps_v_kernel<<<dim3(128), 512, 0, stream>>>(b_state, e_buf, W, w_scale, bias_vec,
                                               alpha, v_buf, vn_buf);
  logits_kernel<<<dim3(782, 4), 512, 0, stream>>>(vn_buf, Ebf, out);
}